// Round 1
// baseline (3309.126 us; speedup 1.0000x reference)
//
#include <hip/hip_runtime.h>

#define NB 8
#define C  64
#define H  128
#define W  128
#define HW (H * W)
#define TOTAL (NB * C * HW)

// -------------------------------------------------------------------------
// Kernel A: h = conv3x3(y, w1, pad=1) + b1      (NCHW, OIHW)
// One thread per output element. Warp covers consecutive w -> coalesced y
// reads per input channel; w1 reads are wave-uniform (same c across wave).
// -------------------------------------------------------------------------
__global__ __launch_bounds__(256) void conv3x3_kernel(
    const float* __restrict__ y,
    const float* __restrict__ w1,
    const float* __restrict__ b1,
    float* __restrict__ hbuf)
{
    int tid = blockIdx.x * blockDim.x + threadIdx.x;
    if (tid >= TOTAL) return;
    int wq = tid & (W - 1);
    int hp = (tid >> 7) & (H - 1);
    int c  = (tid >> 14) & (C - 1);
    int n  = tid >> 20;

    const float* yb = y + (size_t)n * C * HW;
    const float* wb = w1 + (size_t)c * C * 9;

    float acc = b1[c];
    #pragma unroll 4
    for (int k = 0; k < C; ++k) {
        const float* yk = yb + k * HW;
        const float* wk = wb + k * 9;
        #pragma unroll
        for (int di = 0; di < 3; ++di) {
            int hh = hp + di - 1;
            bool okh = (unsigned)hh < (unsigned)H;
            #pragma unroll
            for (int dj = 0; dj < 3; ++dj) {
                int ww = wq + dj - 1;
                bool ok = okh && ((unsigned)ww < (unsigned)W);
                float yv = ok ? yk[hh * W + ww] : 0.0f;
                acc = fmaf(yv, wk[di * 3 + dj], acc);
            }
        }
    }
    hbuf[tid] = acc;
}

// -------------------------------------------------------------------------
// Kernel B: fused 1x1-conv (h -> per-pixel 9-tap kernel) + dynamic conv.
// out[n,c,p,q] = sum_t ( w2[c*9+t,:] . h[n,:,p,q] + b2[c*9+t] ) * xpatch_t
// hvec (64 floats) kept in registers; the (N,576,H,W) kernel tensor is
// never materialized.
// -------------------------------------------------------------------------
__global__ __launch_bounds__(256) void dynconv_kernel(
    const float* __restrict__ x,
    const float* __restrict__ hbuf,
    const float* __restrict__ w2,
    const float* __restrict__ b2,
    float* __restrict__ out)
{
    int tid = blockIdx.x * blockDim.x + threadIdx.x;
    if (tid >= TOTAL) return;
    int wq = tid & (W - 1);
    int hp = (tid >> 7) & (H - 1);
    int c  = (tid >> 14) & (C - 1);
    int n  = tid >> 20;

    // load h[n, :, hp, wq] into registers (coalesced per k across the wave)
    const float* hb = hbuf + (size_t)n * C * HW + hp * W + wq;
    float hv[C];
    #pragma unroll
    for (int k = 0; k < C; ++k) hv[k] = hb[k * HW];

    const float* xb = x + ((size_t)n * C + c) * HW;

    float acc = 0.0f;
    #pragma unroll
    for (int t = 0; t < 9; ++t) {
        int di = t / 3 - 1;
        int dj = t % 3 - 1;
        int hh = hp + di;
        int ww = wq + dj;
        bool ok = ((unsigned)hh < (unsigned)H) && ((unsigned)ww < (unsigned)W);
        float xv = ok ? xb[hh * W + ww] : 0.0f;

        const float* w2r = w2 + (c * 9 + t) * C;  // wave-uniform row
        float ker = b2[c * 9 + t];
        #pragma unroll
        for (int k = 0; k < C; ++k) {
            ker = fmaf(w2r[k], hv[k], ker);
        }
        acc = fmaf(ker, xv, acc);
    }
    out[tid] = acc;
}

extern "C" void kernel_launch(void* const* d_in, const int* in_sizes, int n_in,
                              void* d_out, int out_size, void* d_ws, size_t ws_size,
                              hipStream_t stream)
{
    const float* x  = (const float*)d_in[0];
    const float* y  = (const float*)d_in[1];
    const float* w1 = (const float*)d_in[2];
    const float* b1 = (const float*)d_in[3];
    const float* w2 = (const float*)d_in[4];
    const float* b2 = (const float*)d_in[5];
    float* out = (float*)d_out;
    float* hbuf = (float*)d_ws;  // needs NB*C*HW*4 = 32 MB

    int blocks = TOTAL / 256;
    conv3x3_kernel<<<blocks, 256, 0, stream>>>(y, w1, b1, hbuf);
    dynconv_kernel<<<blocks, 256, 0, stream>>>(x, hbuf, w2, b2, out);
}